// Round 2
// baseline (406.384 us; speedup 1.0000x reference)
//
#include <hip/hip_runtime.h>

typedef _Float16 f16;
typedef _Float16 f16x8 __attribute__((ext_vector_type(8)));
typedef float f32x4 __attribute__((ext_vector_type(4)));
typedef unsigned long long u64;

#define B_ 8
#define N_ 8192
#define S_ 2048
#define D1_ 128
#define D2_ 256
#define M_ (B_ * N_)  // 65536 rows

__device__ __forceinline__ u64 u64min_(u64 a, u64 b) { return a < b ? a : b; }
__device__ __forceinline__ u64 u64max_(u64 a, u64 b) { return a > b ? a : b; }

// ---------------- f32 -> f16 convert (weights) ----------------
__global__ __launch_bounds__(256) void cvt_f32_to_f16(const float* __restrict__ src,
                                                      f16* __restrict__ dst, int n) {
  int i = blockIdx.x * 256 + threadIdx.x;
  if (i < n) dst[i] = (f16)src[i];
}

// ---------------- points2 [B,256,2048] f32 -> f2t [B,2048,256] f16 ----------------
__global__ __launch_bounds__(256) void pts2_to_f2t(const float* __restrict__ points2,
                                                   f16* __restrict__ f2t) {
  __shared__ float tile[64][65];
  int t = threadIdx.x;
  int g = blockIdx.x;            // 8 * 32 * 4 = 1024
  int b = g >> 7;
  int rem = g & 127;
  int s0 = (rem >> 2) * 64;
  int d0 = (rem & 3) * 64;
  int lane = t & 63, q = t >> 6;
  const float* src = points2 + (size_t)b * D2_ * S_;
  for (int dl = q; dl < 64; dl += 4)
    tile[dl][lane] = src[(size_t)(d0 + dl) * S_ + s0 + lane];
  __syncthreads();
  for (int sl = q; sl < 64; sl += 4)
    f2t[((size_t)b * S_ + s0 + sl) * D2_ + d0 + lane] = (f16)tile[lane][sl];
}

// ---------------- points1 [B,128,8192] f32 -> X1[:, 0:128] f16 ----------------
__global__ __launch_bounds__(256) void pts1_to_x1(const float* __restrict__ points1,
                                                  f16* __restrict__ X1) {
  __shared__ float tile[64][65];
  int t = threadIdx.x;
  int g = blockIdx.x;            // 8 * 128 * 2 = 2048
  int b = g >> 8;
  int rem = g & 255;
  int n0 = (rem >> 1) * 64;
  int c0 = (rem & 1) * 64;
  int lane = t & 63, q = t >> 6;
  const float* src = points1 + (size_t)b * D1_ * N_;
  for (int cl = q; cl < 64; cl += 4)
    tile[cl][lane] = src[(size_t)(c0 + cl) * N_ + n0 + lane];
  __syncthreads();
  for (int nl = q; nl < 64; nl += 4)
    X1[((size_t)b * N_ + n0 + nl) * 384 + c0 + lane] = (f16)tile[lane][nl];
}

// ---------------- 3-NN in f64: key = (d64_bits & ~0x7FF) | s ----------------
// f64 distances give the true ordering (noise 2^-41 relative vs typical
// 3rd/4th-NN gap ~1e-2) so selection matches the numpy reference regardless
// of its f32/f64 formula. Low 11 mantissa bits hold the index for stable ties.
__global__ __launch_bounds__(256) void knn3(const float* __restrict__ xyz1,
                                            const float* __restrict__ xyz2,
                                            int* __restrict__ idx3, float* __restrict__ w3) {
  __shared__ double lsx[S_], lsy[S_], lsz[S_];   // 48 KB
  __shared__ u64 ck[3][256];                     // 6 KB
  int t = threadIdx.x;
  int b = blockIdx.x >> 7;            // grid = 8 * 128 = 1024
  int n0 = (blockIdx.x & 127) * 64;
  const float* x2 = xyz2 + (size_t)b * 3 * S_;
  for (int i = t; i < S_; i += 256) {
    lsx[i] = (double)x2[i];
    lsy[i] = (double)x2[S_ + i];
    lsz[i] = (double)x2[2 * S_ + i];
  }
  __syncthreads();
  int nl = t & 63, chunk = t >> 6;    // one wave per chunk: s is wave-uniform -> LDS broadcast
  int n = n0 + nl;
  const float* x1 = xyz1 + (size_t)b * 3 * N_;
  double px = (double)x1[n], py = (double)x1[N_ + n], pz = (double)x1[2 * N_ + n];
  u64 k0 = ~0ull, k1 = ~0ull, k2 = ~0ull;
  int sbeg = chunk * 512;
  for (int s = sbeg; s < sbeg + 512; ++s) {
    double dx = px - lsx[s], dy = py - lsy[s], dz = pz - lsz[s];
    double d = dx * dx + dy * dy + dz * dz;   // >= 0, sign bit clear
    u64 kb = (__double_as_longlong(d) & 0xFFFFFFFFFFFFF800ull) | (u64)(unsigned)s;
    u64 t1 = u64max_(kb, k0); k0 = u64min_(kb, k0);
    u64 t2 = u64max_(t1, k1); k1 = u64min_(t1, k1);
    k2 = u64min_(t2, k2);
  }
  ck[0][t] = k0; ck[1][t] = k1; ck[2][t] = k2;
  __syncthreads();
  if (t < 64) {
    u64 e0 = ck[0][t], e1 = ck[1][t], e2 = ck[2][t];
    #pragma unroll
    for (int ch = 1; ch < 4; ++ch) {
      #pragma unroll
      for (int j = 0; j < 3; ++j) {
        u64 kb = ck[j][t + ch * 64];
        u64 t1 = u64max_(kb, e0); e0 = u64min_(kb, e0);
        u64 t2 = u64max_(t1, e1); e1 = u64min_(t1, e1);
        e2 = u64min_(t2, e2);
      }
    }
    double d0 = __longlong_as_double((long long)(e0 & 0xFFFFFFFFFFFFF800ull));
    double d1 = __longlong_as_double((long long)(e1 & 0xFFFFFFFFFFFFF800ull));
    double d2 = __longlong_as_double((long long)(e2 & 0xFFFFFFFFFFFFF800ull));
    d0 = d0 > 1e-10 ? d0 : 1e-10;
    d1 = d1 > 1e-10 ? d1 : 1e-10;
    d2 = d2 > 1e-10 ? d2 : 1e-10;
    double w0 = 1.0 / d0, w1 = 1.0 / d1, w2 = 1.0 / d2;
    double inv = 1.0 / (w0 + w1 + w2);
    size_t row = (size_t)b * N_ + n0 + t;
    idx3[row * 3 + 0] = (int)(e0 & 0x7FFull);
    idx3[row * 3 + 1] = (int)(e1 & 0x7FFull);
    idx3[row * 3 + 2] = (int)(e2 & 0x7FFull);
    w3[row * 3 + 0] = (float)(w0 * inv);
    w3[row * 3 + 1] = (float)(w1 * inv);
    w3[row * 3 + 2] = (float)(w2 * inv);
  }
}

// ---------------- gather 3 neighbor rows, weighted sum -> X1[:, 128:384] ----------------
__global__ __launch_bounds__(256) void gather_interp(const f16* __restrict__ f2t,
                                                     const int* __restrict__ idx3,
                                                     const float* __restrict__ w3,
                                                     f16* __restrict__ X1) {
  int t = threadIdx.x;
  int w = t >> 6, lane = t & 63;
  size_t row = (size_t)blockIdx.x * 4 + w;   // grid = 16384
  int b = (int)(row >> 13);
  int i0 = idx3[row * 3], i1 = idx3[row * 3 + 1], i2 = idx3[row * 3 + 2];
  float w0 = w3[row * 3], w1 = w3[row * 3 + 1], w2 = w3[row * 3 + 2];
  const f16* base = f2t + (size_t)b * S_ * D2_;
  const f16* r0 = base + (size_t)i0 * D2_;
  const f16* r1 = base + (size_t)i1 * D2_;
  const f16* r2 = base + (size_t)i2 * D2_;
  f16* dst = X1 + row * 384 + 128;
  #pragma unroll
  for (int j = 0; j < 4; ++j) {
    int d = j * 64 + lane;
    float v = w0 * (float)r0[d] + w1 * (float)r1[d] + w2 * (float)r2[d];
    dst[d] = (f16)v;
  }
}

// ---------------- GEMM: C[M,Nn] = A[M,K] * Bt[Nn,K]^T, f16 in, f16/f32 out ----------------
// 128x128 block tile, 4 waves in 2x2, each wave 4x4 16x16x32 MFMA tiles. LDS pitch 72 (pad 8).
template <bool OUT_HALF>
__global__ __launch_bounds__(256) void gemm_bt(const f16* __restrict__ A,
                                               const f16* __restrict__ Bt,
                                               void* __restrict__ Cout, int Nn, int K) {
  __shared__ __align__(16) f16 sA[128 * 72];
  __shared__ __align__(16) f16 sB[128 * 72];
  const int tid = threadIdx.x;
  const int lane = tid & 63;
  const int wave = tid >> 6;
  const int wm = wave & 1, wn = wave >> 1;
  const int lrow = lane & 15, lq = lane >> 4;
  const size_t row0 = (size_t)blockIdx.x * 128;
  const int col0 = blockIdx.y * 128;
  const int srow = tid >> 3, scol = tid & 7;

  f32x4 acc[4][4] = {};

  for (int k0 = 0; k0 < K; k0 += 64) {
    __syncthreads();
    #pragma unroll
    for (int i = 0; i < 4; ++i) {
      int r = srow + i * 32;
      uint4 va = *(const uint4*)(A + (row0 + r) * (size_t)K + k0 + scol * 8);
      uint4 vb = *(const uint4*)(Bt + (size_t)(col0 + r) * K + k0 + scol * 8);
      *(uint4*)(sA + r * 72 + scol * 8) = va;
      *(uint4*)(sB + r * 72 + scol * 8) = vb;
    }
    __syncthreads();
    #pragma unroll
    for (int kc = 0; kc < 2; ++kc) {
      f16x8 af[4], bfr[4];
      #pragma unroll
      for (int mi = 0; mi < 4; ++mi)
        af[mi] = *(const f16x8*)(sA + (wm * 64 + mi * 16 + lrow) * 72 + kc * 32 + lq * 8);
      #pragma unroll
      for (int ni = 0; ni < 4; ++ni)
        bfr[ni] = *(const f16x8*)(sB + (wn * 64 + ni * 16 + lrow) * 72 + kc * 32 + lq * 8);
      #pragma unroll
      for (int mi = 0; mi < 4; ++mi)
        #pragma unroll
        for (int ni = 0; ni < 4; ++ni)
          acc[mi][ni] = __builtin_amdgcn_mfma_f32_16x16x32_f16(af[mi], bfr[ni], acc[mi][ni], 0, 0, 0);
    }
  }

  #pragma unroll
  for (int mi = 0; mi < 4; ++mi)
    #pragma unroll
    for (int ni = 0; ni < 4; ++ni)
      #pragma unroll
      for (int r = 0; r < 4; ++r) {
        size_t row = row0 + wm * 64 + mi * 16 + lq * 4 + r;
        int col = col0 + wn * 64 + ni * 16 + lrow;
        float v = acc[mi][ni][r];
        if (OUT_HALF) ((f16*)Cout)[row * Nn + col] = (f16)v;
        else          ((float*)Cout)[row * Nn + col] = v;
      }
}

// ---------------- per-column sum / sumsq (f16 input, C=256) ----------------
__global__ __launch_bounds__(256) void col_stats_f16(const f16* __restrict__ Y,
                                                     float* __restrict__ stats) {
  int t = threadIdx.x;
  int cp = t & 127;   // uint (2xf16) column
  int rg = t >> 7;
  const unsigned* Yu = (const unsigned*)Y;
  int r0 = blockIdx.x * 128;  // grid = 512
  float s1a = 0, s2a = 0, s1b = 0, s2b = 0;
  for (int r = r0 + rg; r < r0 + 128; r += 2) {
    union { unsigned u; f16 h[2]; } cv;
    cv.u = Yu[(size_t)r * 128 + cp];
    float y0 = (float)cv.h[0], y1 = (float)cv.h[1];
    s1a += y0; s2a += y0 * y0;
    s1b += y1; s2b += y1 * y1;
  }
  __shared__ float red[4][256];
  red[0][t] = s1a; red[1][t] = s2a; red[2][t] = s1b; red[3][t] = s2b;
  __syncthreads();
  if (t < 128) {
    float a = red[0][t] + red[0][t + 128];
    float bq = red[1][t] + red[1][t + 128];
    float c = red[2][t] + red[2][t + 128];
    float d = red[3][t] + red[3][t + 128];
    int c0 = t * 2;
    atomicAdd(&stats[c0], a);       atomicAdd(&stats[256 + c0], bq);
    atomicAdd(&stats[c0 + 1], c);   atomicAdd(&stats[256 + c0 + 1], d);
  }
}

// ---------------- per-column sum / sumsq (f32 input, C=128) ----------------
__global__ __launch_bounds__(256) void col_stats_f32(const float* __restrict__ Y,
                                                     float* __restrict__ stats2) {
  int t = threadIdx.x;
  int c = t & 127;
  int rg = t >> 7;
  int r0 = blockIdx.x * 128;  // grid = 512
  float s1 = 0, s2 = 0;
  for (int r = r0 + rg; r < r0 + 128; r += 2) {
    float y = Y[(size_t)r * 128 + c];
    s1 += y; s2 += y * y;
  }
  __shared__ float red[2][256];
  red[0][t] = s1; red[1][t] = s2;
  __syncthreads();
  if (t < 128) {
    atomicAdd(&stats2[c], red[0][t] + red[0][t + 128]);
    atomicAdd(&stats2[128 + c], red[1][t] + red[1][t + 128]);
  }
}

// ---------------- BN1 + ReLU, f16 -> f16 (X2) ----------------
__global__ __launch_bounds__(256) void bn1_apply(const f16* __restrict__ Y1, f16* __restrict__ X2,
                                                 const float* __restrict__ stats,
                                                 const float* __restrict__ g1,
                                                 const float* __restrict__ be1) {
  __shared__ float sc[D2_], sh[D2_];
  int t = threadIdx.x;
  const float invM = 1.0f / (float)M_;
  if (t < D2_) {
    float m = stats[t] * invM;
    float v = stats[D2_ + t] * invM - m * m;
    float s = rsqrtf(fmaxf(v, 0.f) + 1e-5f) * g1[t];
    sc[t] = s; sh[t] = be1[t] - m * s;
  }
  __syncthreads();
  size_t i0 = (size_t)blockIdx.x * 256 + t;  // grid = 2048
  int c0 = (int)((i0 * 8) & (D2_ - 1));
  float scr[8], shr[8];
  #pragma unroll
  for (int j = 0; j < 8; ++j) { scr[j] = sc[c0 + j]; shr[j] = sh[c0 + j]; }
  const size_t total = (size_t)M_ * D2_ / 8;
  const size_t stride = (size_t)gridDim.x * 256;
  for (size_t i = i0; i < total; i += stride) {
    f16x8 y = ((const f16x8*)Y1)[i];
    f16x8 o;
    #pragma unroll
    for (int j = 0; j < 8; ++j) {
      float v = (float)y[j] * scr[j] + shr[j];
      o[j] = (f16)fmaxf(v, 0.f);
    }
    ((f16x8*)X2)[i] = o;
  }
}

// ---------------- BN2 + ReLU + transpose to out [B,128,N] f32 ----------------
__global__ __launch_bounds__(256) void bn2_transpose(const float* __restrict__ Y2,
                                                     float* __restrict__ out,
                                                     const float* __restrict__ stats2,
                                                     const float* __restrict__ g2,
                                                     const float* __restrict__ be2) {
  __shared__ float sc[D1_], sh[D1_];
  __shared__ float tile[64][D1_ + 1];
  int t = threadIdx.x;
  const float invM = 1.0f / (float)M_;
  if (t < D1_) {
    float m = stats2[t] * invM;
    float v = stats2[D1_ + t] * invM - m * m;
    float s = rsqrtf(fmaxf(v, 0.f) + 1e-5f) * g2[t];
    sc[t] = s; sh[t] = be2[t] - m * s;
  }
  __syncthreads();
  int b = blockIdx.x >> 7;            // grid = 1024
  int n0 = (blockIdx.x & 127) * 64;
  const float* src = Y2 + ((size_t)b * N_ + n0) * D1_;
  for (int i = t; i < 64 * D1_; i += 256) {
    int nl = i >> 7, c = i & (D1_ - 1);
    float y = src[(size_t)nl * D1_ + c];
    tile[nl][c] = fmaxf(y * sc[c] + sh[c], 0.f);
  }
  __syncthreads();
  for (int i = t; i < 64 * D1_; i += 256) {
    int c = i >> 6, nl = i & 63;
    out[((size_t)b * D1_ + c) * N_ + n0 + nl] = tile[nl][c];
  }
}

extern "C" void kernel_launch(void* const* d_in, const int* in_sizes, int n_in,
                              void* d_out, int out_size, void* d_ws, size_t ws_size,
                              hipStream_t stream) {
  const float* xyz1    = (const float*)d_in[0];
  const float* xyz2    = (const float*)d_in[1];
  const float* points1 = (const float*)d_in[2];
  const float* points2 = (const float*)d_in[3];
  const float* w1      = (const float*)d_in[4];
  const float* g1      = (const float*)d_in[6];
  const float* be1     = (const float*)d_in[7];
  const float* w2      = (const float*)d_in[8];
  const float* g2      = (const float*)d_in[10];
  const float* be2     = (const float*)d_in[11];
  float* out = (float*)d_out;

  char* ws = (char*)d_ws;
  f16*   f2t   = (f16*)(ws);                  // [B,S,256] f16:   8,388,608 B
  int*   idx3  = (int*)(ws + 8388608);        // [M,3] int:         786,432
  float* w3    = (float*)(ws + 9175040);      // [M,3] f32:         786,432
  f16*   W1h   = (f16*)(ws + 9961472);        // [256,384] f16:     196,608
  f16*   W2h   = (f16*)(ws + 10158080);       // [128,256] f16:      65,536
  float* stats = (float*)(ws + 10223616);     // 768 f32 used:        4,096
  f16*   X1    = (f16*)(ws + 10227712);       // [M,384] f16: 50,331,648 (X2 reuses)
  f16*   Y1    = (f16*)(ws + 60559360);       // [M,256] f16: 33,554,432 (Y2 f32 reuses)
  float* Y2    = (float*)Y1;
  f16*   X2    = X1;

  hipMemsetAsync(stats, 0, 768 * sizeof(float), stream);
  cvt_f32_to_f16<<<384, 256, 0, stream>>>(w1, W1h, 256 * 384);
  cvt_f32_to_f16<<<128, 256, 0, stream>>>(w2, W2h, 128 * 256);
  pts2_to_f2t<<<1024, 256, 0, stream>>>(points2, f2t);
  knn3<<<1024, 256, 0, stream>>>(xyz1, xyz2, idx3, w3);
  gather_interp<<<16384, 256, 0, stream>>>(f2t, idx3, w3, X1);
  pts1_to_x1<<<2048, 256, 0, stream>>>(points1, X1);
  gemm_bt<true><<<dim3(512, 2), 256, 0, stream>>>(X1, W1h, (void*)Y1, 256, 384);
  col_stats_f16<<<512, 256, 0, stream>>>(Y1, stats);
  bn1_apply<<<2048, 256, 0, stream>>>(Y1, X2, stats, g1, be1);
  gemm_bt<false><<<dim3(512, 1), 256, 0, stream>>>(X2, W2h, (void*)Y2, 128, 256);
  col_stats_f32<<<512, 256, 0, stream>>>(Y2, stats + 512);
  bn2_transpose<<<1024, 256, 0, stream>>>(Y2, out, stats + 512, g2, be2);
}

// Round 3
// 354.162 us; speedup vs baseline: 1.1475x; 1.1475x over previous
//
#include <hip/hip_runtime.h>

typedef _Float16 f16;
typedef _Float16 f16x8 __attribute__((ext_vector_type(8)));
typedef float f32x4 __attribute__((ext_vector_type(4)));
typedef unsigned long long u64;

#define B_ 8
#define N_ 8192
#define S_ 2048
#define D1_ 128
#define D2_ 256
#define M_ (B_ * N_)  // 65536 rows

__device__ __forceinline__ u64 u64min_(u64 a, u64 b) { return a < b ? a : b; }
__device__ __forceinline__ u64 u64max_(u64 a, u64 b) { return a > b ? a : b; }
__device__ __forceinline__ unsigned umin_(unsigned a, unsigned b) { return a < b ? a : b; }
__device__ __forceinline__ unsigned umax_(unsigned a, unsigned b) { return a > b ? a : b; }

// ---------------- f32 -> f16 convert (weights) ----------------
__global__ __launch_bounds__(256) void cvt_f32_to_f16(const float* __restrict__ src,
                                                      f16* __restrict__ dst, int n) {
  int i = blockIdx.x * 256 + threadIdx.x;
  if (i < n) dst[i] = (f16)src[i];
}

// ---------------- points2 [B,256,2048] f32 -> f2t [B,2048,256] f16 ----------------
__global__ __launch_bounds__(256) void pts2_to_f2t(const float* __restrict__ points2,
                                                   f16* __restrict__ f2t) {
  __shared__ float tile[64][65];
  int t = threadIdx.x;
  int g = blockIdx.x;            // 8 * 32 * 4 = 1024
  int b = g >> 7;
  int rem = g & 127;
  int s0 = (rem >> 2) * 64;
  int d0 = (rem & 3) * 64;
  int lane = t & 63, q = t >> 6;
  const float* src = points2 + (size_t)b * D2_ * S_;
  for (int dl = q; dl < 64; dl += 4)
    tile[dl][lane] = src[(size_t)(d0 + dl) * S_ + s0 + lane];
  __syncthreads();
  for (int sl = q; sl < 64; sl += 4)
    f2t[((size_t)b * S_ + s0 + sl) * D2_ + d0 + lane] = (f16)tile[lane][sl];
}

// ---------------- points1 [B,128,8192] f32 -> X1[:, 0:128] f16 ----------------
__global__ __launch_bounds__(256) void pts1_to_x1(const float* __restrict__ points1,
                                                  f16* __restrict__ X1) {
  __shared__ float tile[64][65];
  int t = threadIdx.x;
  int g = blockIdx.x;            // 8 * 128 * 2 = 2048
  int b = g >> 8;
  int rem = g & 255;
  int n0 = (rem >> 1) * 64;
  int c0 = (rem & 1) * 64;
  int lane = t & 63, q = t >> 6;
  const float* src = points1 + (size_t)b * D1_ * N_;
  for (int cl = q; cl < 64; cl += 4)
    tile[cl][lane] = src[(size_t)(c0 + cl) * N_ + n0 + lane];
  __syncthreads();
  for (int nl = q; nl < 64; nl += 4)
    X1[((size_t)b * N_ + n0 + nl) * 384 + c0 + lane] = (f16)tile[lane][nl];
}

// ---------------- 3-NN: f32 top-6 filter + f64 rescore of survivors ----------------
// Pass A keeps a sorted top-6 of keys (f32_dist_bits & ~0x7FF) | s  (u32 min/max
// network, single-instr each). Wrong final top-3 needs >=4 spurious candidates
// inside the 2.4e-4 truncation window around d3: P ~ 1e-14 over all points.
// Pass B rescores the 6 survivors in f64 (exact formula) -> true ordering,
// identical selection to the previous all-f64 kernel.
__global__ __launch_bounds__(256) void knn3(const float* __restrict__ xyz1,
                                            const float* __restrict__ xyz2,
                                            int* __restrict__ idx3, float* __restrict__ w3) {
  __shared__ float4 ls[S_];           // 32 KB: (x,y,z,0)
  __shared__ unsigned ck[6][256];     // 6 KB
  int t = threadIdx.x;
  int b = blockIdx.x >> 7;            // grid = 8 * 128 = 1024
  int n0 = (blockIdx.x & 127) * 64;
  const float* x2 = xyz2 + (size_t)b * 3 * S_;
  for (int i = t; i < S_; i += 256)
    ls[i] = make_float4(x2[i], x2[S_ + i], x2[2 * S_ + i], 0.f);
  __syncthreads();
  int nl = t & 63, chunk = t >> 6;    // one wave per chunk: s wave-uniform -> LDS broadcast
  int n = n0 + nl;
  const float* x1 = xyz1 + (size_t)b * 3 * N_;
  float px = x1[n], py = x1[N_ + n], pz = x1[2 * N_ + n];
  unsigned kk[6];
  #pragma unroll
  for (int j = 0; j < 6; ++j) kk[j] = 0xFFFFFFFFu;
  int sbeg = chunk * 512;
  for (int s = sbeg; s < sbeg + 512; ++s) {
    float4 q = ls[s];
    float dx = px - q.x, dy = py - q.y, dz = pz - q.z;
    float d = dx * dx + dy * dy + dz * dz;
    unsigned x = (__float_as_uint(d) & 0xFFFFF800u) | (unsigned)s;
    #pragma unroll
    for (int j = 0; j < 6; ++j) {
      unsigned hi = umax_(x, kk[j]);
      kk[j] = umin_(x, kk[j]);
      x = hi;
    }
  }
  #pragma unroll
  for (int j = 0; j < 6; ++j) ck[j][t] = kk[j];
  __syncthreads();
  if (t < 64) {
    unsigned e[6];
    #pragma unroll
    for (int j = 0; j < 6; ++j) e[j] = ck[j][t];
    #pragma unroll
    for (int ch = 1; ch < 4; ++ch) {
      #pragma unroll
      for (int j = 0; j < 6; ++j) {
        unsigned x = ck[j][t + ch * 64];
        #pragma unroll
        for (int jj = 0; jj < 6; ++jj) {
          unsigned hi = umax_(x, e[jj]);
          e[jj] = umin_(x, e[jj]);
          x = hi;
        }
      }
    }
    // f64 rescore of the 6 survivors (s-ranges per chunk are disjoint -> no dups)
    float qx = px;  // t<64 <=> chunk 0, nl == t, so px/py/pz are this query's coords
    double ppx = (double)px, ppy = (double)py, ppz = (double)pz;
    (void)qx;
    u64 k0 = ~0ull, k1 = ~0ull, k2 = ~0ull;
    #pragma unroll
    for (int i = 0; i < 6; ++i) {
      unsigned si = e[i] & 0x7FFu;
      float4 q = ls[si];
      double dx = ppx - (double)q.x, dy = ppy - (double)q.y, dz = ppz - (double)q.z;
      double d = dx * dx + dy * dy + dz * dz;
      u64 kb = (__double_as_longlong(d) & 0xFFFFFFFFFFFFF800ull) | (u64)si;
      u64 t1 = u64max_(kb, k0); k0 = u64min_(kb, k0);
      u64 t2 = u64max_(t1, k1); k1 = u64min_(t1, k1);
      k2 = u64min_(t2, k2);
    }
    double d0 = __longlong_as_double((long long)(k0 & 0xFFFFFFFFFFFFF800ull));
    double d1 = __longlong_as_double((long long)(k1 & 0xFFFFFFFFFFFFF800ull));
    double d2 = __longlong_as_double((long long)(k2 & 0xFFFFFFFFFFFFF800ull));
    d0 = d0 > 1e-10 ? d0 : 1e-10;
    d1 = d1 > 1e-10 ? d1 : 1e-10;
    d2 = d2 > 1e-10 ? d2 : 1e-10;
    double w0 = 1.0 / d0, w1 = 1.0 / d1, w2 = 1.0 / d2;
    double inv = 1.0 / (w0 + w1 + w2);
    size_t row = (size_t)b * N_ + n0 + t;
    idx3[row * 3 + 0] = (int)(k0 & 0x7FFull);
    idx3[row * 3 + 1] = (int)(k1 & 0x7FFull);
    idx3[row * 3 + 2] = (int)(k2 & 0x7FFull);
    w3[row * 3 + 0] = (float)(w0 * inv);
    w3[row * 3 + 1] = (float)(w1 * inv);
    w3[row * 3 + 2] = (float)(w2 * inv);
  }
}

// ---------------- gather 3 neighbor rows, weighted sum -> X1[:, 128:384] ----------------
__global__ __launch_bounds__(256) void gather_interp(const f16* __restrict__ f2t,
                                                     const int* __restrict__ idx3,
                                                     const float* __restrict__ w3,
                                                     f16* __restrict__ X1) {
  int t = threadIdx.x;
  int w = t >> 6, lane = t & 63;
  size_t row = (size_t)blockIdx.x * 4 + w;   // grid = 16384
  int b = (int)(row >> 13);
  int i0 = idx3[row * 3], i1 = idx3[row * 3 + 1], i2 = idx3[row * 3 + 2];
  float w0 = w3[row * 3], w1 = w3[row * 3 + 1], w2 = w3[row * 3 + 2];
  const f16* base = f2t + (size_t)b * S_ * D2_;
  const f16* r0 = base + (size_t)i0 * D2_;
  const f16* r1 = base + (size_t)i1 * D2_;
  const f16* r2 = base + (size_t)i2 * D2_;
  f16* dst = X1 + row * 384 + 128;
  #pragma unroll
  for (int j = 0; j < 4; ++j) {
    int d = j * 64 + lane;
    float v = w0 * (float)r0[d] + w1 * (float)r1[d] + w2 * (float)r2[d];
    dst[d] = (f16)v;
  }
}

// ---------------- GEMM: C[M,Nn] = A[M,K] * Bt[Nn,K]^T, f16 in, f16/f32 out ----------------
// 128x128 block tile, 4 waves in 2x2, each wave 4x4 16x16x32 MFMA tiles. LDS pitch 72 (pad 8).
template <bool OUT_HALF>
__global__ __launch_bounds__(256) void gemm_bt(const f16* __restrict__ A,
                                               const f16* __restrict__ Bt,
                                               void* __restrict__ Cout, int Nn, int K) {
  __shared__ __align__(16) f16 sA[128 * 72];
  __shared__ __align__(16) f16 sB[128 * 72];
  const int tid = threadIdx.x;
  const int lane = tid & 63;
  const int wave = tid >> 6;
  const int wm = wave & 1, wn = wave >> 1;
  const int lrow = lane & 15, lq = lane >> 4;
  const size_t row0 = (size_t)blockIdx.x * 128;
  const int col0 = blockIdx.y * 128;
  const int srow = tid >> 3, scol = tid & 7;

  f32x4 acc[4][4] = {};

  for (int k0 = 0; k0 < K; k0 += 64) {
    __syncthreads();
    #pragma unroll
    for (int i = 0; i < 4; ++i) {
      int r = srow + i * 32;
      uint4 va = *(const uint4*)(A + (row0 + r) * (size_t)K + k0 + scol * 8);
      uint4 vb = *(const uint4*)(Bt + (size_t)(col0 + r) * K + k0 + scol * 8);
      *(uint4*)(sA + r * 72 + scol * 8) = va;
      *(uint4*)(sB + r * 72 + scol * 8) = vb;
    }
    __syncthreads();
    #pragma unroll
    for (int kc = 0; kc < 2; ++kc) {
      f16x8 af[4], bfr[4];
      #pragma unroll
      for (int mi = 0; mi < 4; ++mi)
        af[mi] = *(const f16x8*)(sA + (wm * 64 + mi * 16 + lrow) * 72 + kc * 32 + lq * 8);
      #pragma unroll
      for (int ni = 0; ni < 4; ++ni)
        bfr[ni] = *(const f16x8*)(sB + (wn * 64 + ni * 16 + lrow) * 72 + kc * 32 + lq * 8);
      #pragma unroll
      for (int mi = 0; mi < 4; ++mi)
        #pragma unroll
        for (int ni = 0; ni < 4; ++ni)
          acc[mi][ni] = __builtin_amdgcn_mfma_f32_16x16x32_f16(af[mi], bfr[ni], acc[mi][ni], 0, 0, 0);
    }
  }

  #pragma unroll
  for (int mi = 0; mi < 4; ++mi)
    #pragma unroll
    for (int ni = 0; ni < 4; ++ni)
      #pragma unroll
      for (int r = 0; r < 4; ++r) {
        size_t row = row0 + wm * 64 + mi * 16 + lq * 4 + r;
        int col = col0 + wn * 64 + ni * 16 + lrow;
        float v = acc[mi][ni][r];
        if (OUT_HALF) ((f16*)Cout)[row * Nn + col] = (f16)v;
        else          ((float*)Cout)[row * Nn + col] = v;
      }
}

// ---------------- per-column sum / sumsq (f16 input, C=256) ----------------
__global__ __launch_bounds__(256) void col_stats_f16(const f16* __restrict__ Y,
                                                     float* __restrict__ stats) {
  int t = threadIdx.x;
  int cp = t & 127;   // uint (2xf16) column
  int rg = t >> 7;
  const unsigned* Yu = (const unsigned*)Y;
  int r0 = blockIdx.x * 128;  // grid = 512
  float s1a = 0, s2a = 0, s1b = 0, s2b = 0;
  for (int r = r0 + rg; r < r0 + 128; r += 2) {
    union { unsigned u; f16 h[2]; } cv;
    cv.u = Yu[(size_t)r * 128 + cp];
    float y0 = (float)cv.h[0], y1 = (float)cv.h[1];
    s1a += y0; s2a += y0 * y0;
    s1b += y1; s2b += y1 * y1;
  }
  __shared__ float red[4][256];
  red[0][t] = s1a; red[1][t] = s2a; red[2][t] = s1b; red[3][t] = s2b;
  __syncthreads();
  if (t < 128) {
    float a = red[0][t] + red[0][t + 128];
    float bq = red[1][t] + red[1][t + 128];
    float c = red[2][t] + red[2][t + 128];
    float d = red[3][t] + red[3][t + 128];
    int c0 = t * 2;
    atomicAdd(&stats[c0], a);       atomicAdd(&stats[256 + c0], bq);
    atomicAdd(&stats[c0 + 1], c);   atomicAdd(&stats[256 + c0 + 1], d);
  }
}

// ---------------- per-column sum / sumsq (f32 input, C=128) ----------------
__global__ __launch_bounds__(256) void col_stats_f32(const float* __restrict__ Y,
                                                     float* __restrict__ stats2) {
  int t = threadIdx.x;
  int c = t & 127;
  int rg = t >> 7;
  int r0 = blockIdx.x * 128;  // grid = 512
  float s1 = 0, s2 = 0;
  for (int r = r0 + rg; r < r0 + 128; r += 2) {
    float y = Y[(size_t)r * 128 + c];
    s1 += y; s2 += y * y;
  }
  __shared__ float red[2][256];
  red[0][t] = s1; red[1][t] = s2;
  __syncthreads();
  if (t < 128) {
    atomicAdd(&stats2[c], red[0][t] + red[0][t + 128]);
    atomicAdd(&stats2[128 + c], red[1][t] + red[1][t + 128]);
  }
}

// ---------------- BN1 + ReLU, f16 -> f16 (X2) ----------------
__global__ __launch_bounds__(256) void bn1_apply(const f16* __restrict__ Y1, f16* __restrict__ X2,
                                                 const float* __restrict__ stats,
                                                 const float* __restrict__ g1,
                                                 const float* __restrict__ be1) {
  __shared__ float sc[D2_], sh[D2_];
  int t = threadIdx.x;
  const float invM = 1.0f / (float)M_;
  if (t < D2_) {
    float m = stats[t] * invM;
    float v = stats[D2_ + t] * invM - m * m;
    float s = rsqrtf(fmaxf(v, 0.f) + 1e-5f) * g1[t];
    sc[t] = s; sh[t] = be1[t] - m * s;
  }
  __syncthreads();
  size_t i0 = (size_t)blockIdx.x * 256 + t;  // grid = 2048
  int c0 = (int)((i0 * 8) & (D2_ - 1));
  float scr[8], shr[8];
  #pragma unroll
  for (int j = 0; j < 8; ++j) { scr[j] = sc[c0 + j]; shr[j] = sh[c0 + j]; }
  const size_t total = (size_t)M_ * D2_ / 8;
  const size_t stride = (size_t)gridDim.x * 256;
  for (size_t i = i0; i < total; i += stride) {
    f16x8 y = ((const f16x8*)Y1)[i];
    f16x8 o;
    #pragma unroll
    for (int j = 0; j < 8; ++j) {
      float v = (float)y[j] * scr[j] + shr[j];
      o[j] = (f16)fmaxf(v, 0.f);
    }
    ((f16x8*)X2)[i] = o;
  }
}

// ---------------- BN2 + ReLU + transpose to out [B,128,N] f32 ----------------
__global__ __launch_bounds__(256) void bn2_transpose(const float* __restrict__ Y2,
                                                     float* __restrict__ out,
                                                     const float* __restrict__ stats2,
                                                     const float* __restrict__ g2,
                                                     const float* __restrict__ be2) {
  __shared__ float sc[D1_], sh[D1_];
  __shared__ float tile[64][D1_ + 1];
  int t = threadIdx.x;
  const float invM = 1.0f / (float)M_;
  if (t < D1_) {
    float m = stats2[t] * invM;
    float v = stats2[D1_ + t] * invM - m * m;
    float s = rsqrtf(fmaxf(v, 0.f) + 1e-5f) * g2[t];
    sc[t] = s; sh[t] = be2[t] - m * s;
  }
  __syncthreads();
  int b = blockIdx.x >> 7;            // grid = 1024
  int n0 = (blockIdx.x & 127) * 64;
  const float* src = Y2 + ((size_t)b * N_ + n0) * D1_;
  for (int i = t; i < 64 * D1_; i += 256) {
    int nl = i >> 7, c = i & (D1_ - 1);
    float y = src[(size_t)nl * D1_ + c];
    tile[nl][c] = fmaxf(y * sc[c] + sh[c], 0.f);
  }
  __syncthreads();
  for (int i = t; i < 64 * D1_; i += 256) {
    int c = i >> 6, nl = i & 63;
    out[((size_t)b * D1_ + c) * N_ + n0 + nl] = tile[nl][c];
  }
}

extern "C" void kernel_launch(void* const* d_in, const int* in_sizes, int n_in,
                              void* d_out, int out_size, void* d_ws, size_t ws_size,
                              hipStream_t stream) {
  const float* xyz1    = (const float*)d_in[0];
  const float* xyz2    = (const float*)d_in[1];
  const float* points1 = (const float*)d_in[2];
  const float* points2 = (const float*)d_in[3];
  const float* w1      = (const float*)d_in[4];
  const float* g1      = (const float*)d_in[6];
  const float* be1     = (const float*)d_in[7];
  const float* w2      = (const float*)d_in[8];
  const float* g2      = (const float*)d_in[10];
  const float* be2     = (const float*)d_in[11];
  float* out = (float*)d_out;

  char* ws = (char*)d_ws;
  f16*   f2t   = (f16*)(ws);                  // [B,S,256] f16:   8,388,608 B
  int*   idx3  = (int*)(ws + 8388608);        // [M,3] int:         786,432
  float* w3    = (float*)(ws + 9175040);      // [M,3] f32:         786,432
  f16*   W1h   = (f16*)(ws + 9961472);        // [256,384] f16:     196,608
  f16*   W2h   = (f16*)(ws + 10158080);       // [128,256] f16:      65,536
  float* stats = (float*)(ws + 10223616);     // 768 f32 used:        4,096
  f16*   X1    = (f16*)(ws + 10227712);       // [M,384] f16: 50,331,648 (X2 reuses)
  f16*   Y1    = (f16*)(ws + 60559360);       // [M,256] f16: 33,554,432 (Y2 f32 reuses)
  float* Y2    = (float*)Y1;
  f16*   X2    = X1;

  hipMemsetAsync(stats, 0, 768 * sizeof(float), stream);
  cvt_f32_to_f16<<<384, 256, 0, stream>>>(w1, W1h, 256 * 384);
  cvt_f32_to_f16<<<128, 256, 0, stream>>>(w2, W2h, 128 * 256);
  pts2_to_f2t<<<1024, 256, 0, stream>>>(points2, f2t);
  knn3<<<1024, 256, 0, stream>>>(xyz1, xyz2, idx3, w3);
  gather_interp<<<16384, 256, 0, stream>>>(f2t, idx3, w3, X1);
  pts1_to_x1<<<2048, 256, 0, stream>>>(points1, X1);
  gemm_bt<true><<<dim3(512, 2), 256, 0, stream>>>(X1, W1h, (void*)Y1, 256, 384);
  col_stats_f16<<<512, 256, 0, stream>>>(Y1, stats);
  bn1_apply<<<2048, 256, 0, stream>>>(Y1, X2, stats, g1, be1);
  gemm_bt<false><<<dim3(512, 1), 256, 0, stream>>>(X2, W2h, (void*)Y2, 128, 256);
  col_stats_f32<<<512, 256, 0, stream>>>(Y2, stats + 512);
  bn2_transpose<<<1024, 256, 0, stream>>>(Y2, out, stats + 512, g2, be2);
}

// Round 4
// 325.221 us; speedup vs baseline: 1.2496x; 1.0890x over previous
//
#include <hip/hip_runtime.h>

typedef _Float16 f16;
typedef _Float16 f16x8 __attribute__((ext_vector_type(8)));
typedef float f32x4 __attribute__((ext_vector_type(4)));
typedef unsigned long long u64;

#define B_ 8
#define N_ 8192
#define S_ 2048
#define D1_ 128
#define D2_ 256
#define M_ (B_ * N_)  // 65536 rows

__device__ __forceinline__ u64 u64min_(u64 a, u64 b) { return a < b ? a : b; }
__device__ __forceinline__ u64 u64max_(u64 a, u64 b) { return a > b ? a : b; }
__device__ __forceinline__ unsigned umin_(unsigned a, unsigned b) { return a < b ? a : b; }
__device__ __forceinline__ unsigned umax_(unsigned a, unsigned b) { return a > b ? a : b; }

// async global->LDS, 16B per lane. LDS dest is wave-uniform base + lane*16,
// so the LDS layout must be linear in lane order (no padding).
typedef __attribute__((address_space(1))) const unsigned int GUI;
typedef __attribute__((address_space(3))) unsigned int LUI;
__device__ __forceinline__ void gload_lds16(const f16* g, f16* l) {
  __builtin_amdgcn_global_load_lds((GUI*)g, (LUI*)l, 16, 0, 0);
}

// ---------------- f32 -> f16 convert (weights) ----------------
__global__ __launch_bounds__(256) void cvt_f32_to_f16(const float* __restrict__ src,
                                                      f16* __restrict__ dst, int n) {
  int i = blockIdx.x * 256 + threadIdx.x;
  if (i < n) dst[i] = (f16)src[i];
}

// ---------------- points2 [B,256,2048] f32 -> f2t [B,2048,256] f16 ----------------
__global__ __launch_bounds__(256) void pts2_to_f2t(const float* __restrict__ points2,
                                                   f16* __restrict__ f2t) {
  __shared__ float tile[64][65];
  int t = threadIdx.x;
  int g = blockIdx.x;            // 8 * 32 * 4 = 1024
  int b = g >> 7;
  int rem = g & 127;
  int s0 = (rem >> 2) * 64;
  int d0 = (rem & 3) * 64;
  int lane = t & 63, q = t >> 6;
  const float* src = points2 + (size_t)b * D2_ * S_;
  for (int dl = q; dl < 64; dl += 4)
    tile[dl][lane] = src[(size_t)(d0 + dl) * S_ + s0 + lane];
  __syncthreads();
  for (int sl = q; sl < 64; sl += 4)
    f2t[((size_t)b * S_ + s0 + sl) * D2_ + d0 + lane] = (f16)tile[lane][sl];
}

// ---------------- points1 [B,128,8192] f32 -> X1[:, 0:128] f16 ----------------
__global__ __launch_bounds__(256) void pts1_to_x1(const float* __restrict__ points1,
                                                  f16* __restrict__ X1) {
  __shared__ float tile[64][65];
  int t = threadIdx.x;
  int g = blockIdx.x;            // 8 * 128 * 2 = 2048
  int b = g >> 8;
  int rem = g & 255;
  int n0 = (rem >> 1) * 64;
  int c0 = (rem & 1) * 64;
  int lane = t & 63, q = t >> 6;
  const float* src = points1 + (size_t)b * D1_ * N_;
  for (int cl = q; cl < 64; cl += 4)
    tile[cl][lane] = src[(size_t)(c0 + cl) * N_ + n0 + lane];
  __syncthreads();
  for (int nl = q; nl < 64; nl += 4)
    X1[((size_t)b * N_ + n0 + nl) * 384 + c0 + lane] = (f16)tile[lane][nl];
}

// ---------------- 3-NN: f32 top-6 filter + f64 rescore of survivors ----------------
__global__ __launch_bounds__(256) void knn3(const float* __restrict__ xyz1,
                                            const float* __restrict__ xyz2,
                                            int* __restrict__ idx3, float* __restrict__ w3) {
  __shared__ float4 ls[S_];           // 32 KB: (x,y,z,0)
  __shared__ unsigned ck[6][256];     // 6 KB
  int t = threadIdx.x;
  int b = blockIdx.x >> 7;            // grid = 8 * 128 = 1024
  int n0 = (blockIdx.x & 127) * 64;
  const float* x2 = xyz2 + (size_t)b * 3 * S_;
  for (int i = t; i < S_; i += 256)
    ls[i] = make_float4(x2[i], x2[S_ + i], x2[2 * S_ + i], 0.f);
  __syncthreads();
  int nl = t & 63, chunk = t >> 6;    // one wave per chunk: s wave-uniform -> LDS broadcast
  int n = n0 + nl;
  const float* x1 = xyz1 + (size_t)b * 3 * N_;
  float px = x1[n], py = x1[N_ + n], pz = x1[2 * N_ + n];
  unsigned kk[6];
  #pragma unroll
  for (int j = 0; j < 6; ++j) kk[j] = 0xFFFFFFFFu;
  int sbeg = chunk * 512;
  for (int s = sbeg; s < sbeg + 512; ++s) {
    float4 q = ls[s];
    float dx = px - q.x, dy = py - q.y, dz = pz - q.z;
    float d = dx * dx + dy * dy + dz * dz;
    unsigned x = (__float_as_uint(d) & 0xFFFFF800u) | (unsigned)s;
    #pragma unroll
    for (int j = 0; j < 6; ++j) {
      unsigned hi = umax_(x, kk[j]);
      kk[j] = umin_(x, kk[j]);
      x = hi;
    }
  }
  #pragma unroll
  for (int j = 0; j < 6; ++j) ck[j][t] = kk[j];
  __syncthreads();
  if (t < 64) {
    unsigned e[6];
    #pragma unroll
    for (int j = 0; j < 6; ++j) e[j] = ck[j][t];
    #pragma unroll
    for (int ch = 1; ch < 4; ++ch) {
      #pragma unroll
      for (int j = 0; j < 6; ++j) {
        unsigned x = ck[j][t + ch * 64];
        #pragma unroll
        for (int jj = 0; jj < 6; ++jj) {
          unsigned hi = umax_(x, e[jj]);
          e[jj] = umin_(x, e[jj]);
          x = hi;
        }
      }
    }
    double ppx = (double)px, ppy = (double)py, ppz = (double)pz;
    u64 k0 = ~0ull, k1 = ~0ull, k2 = ~0ull;
    #pragma unroll
    for (int i = 0; i < 6; ++i) {
      unsigned si = e[i] & 0x7FFu;
      float4 q = ls[si];
      double dx = ppx - (double)q.x, dy = ppy - (double)q.y, dz = ppz - (double)q.z;
      double d = dx * dx + dy * dy + dz * dz;
      u64 kb = (__double_as_longlong(d) & 0xFFFFFFFFFFFFF800ull) | (u64)si;
      u64 t1 = u64max_(kb, k0); k0 = u64min_(kb, k0);
      u64 t2 = u64max_(t1, k1); k1 = u64min_(t1, k1);
      k2 = u64min_(t2, k2);
    }
    double d0 = __longlong_as_double((long long)(k0 & 0xFFFFFFFFFFFFF800ull));
    double d1 = __longlong_as_double((long long)(k1 & 0xFFFFFFFFFFFFF800ull));
    double d2 = __longlong_as_double((long long)(k2 & 0xFFFFFFFFFFFFF800ull));
    d0 = d0 > 1e-10 ? d0 : 1e-10;
    d1 = d1 > 1e-10 ? d1 : 1e-10;
    d2 = d2 > 1e-10 ? d2 : 1e-10;
    double w0 = 1.0 / d0, w1 = 1.0 / d1, w2 = 1.0 / d2;
    double inv = 1.0 / (w0 + w1 + w2);
    size_t row = (size_t)b * N_ + n0 + t;
    idx3[row * 3 + 0] = (int)(k0 & 0x7FFull);
    idx3[row * 3 + 1] = (int)(k1 & 0x7FFull);
    idx3[row * 3 + 2] = (int)(k2 & 0x7FFull);
    w3[row * 3 + 0] = (float)(w0 * inv);
    w3[row * 3 + 1] = (float)(w1 * inv);
    w3[row * 3 + 2] = (float)(w2 * inv);
  }
}

// ---------------- gather 3 neighbor rows, weighted sum -> X1[:, 128:384] ----------------
__global__ __launch_bounds__(256) void gather_interp(const f16* __restrict__ f2t,
                                                     const int* __restrict__ idx3,
                                                     const float* __restrict__ w3,
                                                     f16* __restrict__ X1) {
  int t = threadIdx.x;
  int w = t >> 6, lane = t & 63;
  size_t row = (size_t)blockIdx.x * 4 + w;   // grid = 16384
  int b = (int)(row >> 13);
  int i0 = idx3[row * 3], i1 = idx3[row * 3 + 1], i2 = idx3[row * 3 + 2];
  float w0 = w3[row * 3], w1 = w3[row * 3 + 1], w2 = w3[row * 3 + 2];
  const f16* base = f2t + (size_t)b * S_ * D2_;
  const f16* r0 = base + (size_t)i0 * D2_;
  const f16* r1 = base + (size_t)i1 * D2_;
  const f16* r2 = base + (size_t)i2 * D2_;
  f16* dst = X1 + row * 384 + 128;
  #pragma unroll
  for (int j = 0; j < 4; ++j) {
    int d = j * 64 + lane;
    float v = w0 * (float)r0[d] + w1 * (float)r1[d] + w2 * (float)r2[d];
    dst[d] = (f16)v;
  }
}

// ---------------- GEMM1 fused: Y1[M,256] = X1[M,384] * W1h^T, f16 acc-f32,
// stats epilogue: per-column sum/sumsq atomics. 128x256 tile, A read once,
// global_load_lds width-16 staging (linear LDS layout, pitch 64 halves). ----
__global__ __launch_bounds__(256) void gemm1_fused(const f16* __restrict__ A,
                                                   const f16* __restrict__ Bt,
                                                   f16* __restrict__ Y1,
                                                   float* __restrict__ stats) {
  __shared__ __align__(16) f16 sA[128 * 64];   // 16 KB
  __shared__ __align__(16) f16 sB[256 * 64];   // 32 KB
  const int tid = threadIdx.x;
  const int lane = tid & 63;
  const int wave = tid >> 6;
  const int wm = wave & 1, wn = wave >> 1;     // 2x2: wm rows (64), wn col-half (128)
  const int lrow = lane & 15, lq = lane >> 4;
  const size_t row0 = (size_t)blockIdx.x * 128;

  // staging geometry: lane handles 16B; per wave-instr 1024B contiguous LDS
  const int srow8 = wave * 8 + (lane >> 3);    // + i*32
  const int kb8 = (lane & 7) * 8;              // halves within 64-half K slice
  const f16* agp = A + (row0 + srow8) * 384 + kb8;
  const f16* bgp = Bt + (size_t)srow8 * 384 + kb8;
  f16* alp = sA + srow8 * 64 + kb8;
  f16* blp = sB + srow8 * 64 + kb8;

  f32x4 acc[4][8] = {};

  for (int k0 = 0; k0 < 384; k0 += 64) {
    __syncthreads();
    #pragma unroll
    for (int i = 0; i < 4; ++i)
      gload_lds16(agp + (size_t)i * 32 * 384 + k0, alp + i * 32 * 64);
    #pragma unroll
    for (int i = 0; i < 8; ++i)
      gload_lds16(bgp + (size_t)i * 32 * 384 + k0, blp + i * 32 * 64);
    __syncthreads();   // compiler drains vmcnt before barrier -> LDS ready
    #pragma unroll
    for (int kc = 0; kc < 2; ++kc) {
      f16x8 af[4], bf[8];
      #pragma unroll
      for (int mi = 0; mi < 4; ++mi)
        af[mi] = *(const f16x8*)(sA + (wm * 64 + mi * 16 + lrow) * 64 + kc * 32 + lq * 8);
      #pragma unroll
      for (int ni = 0; ni < 8; ++ni)
        bf[ni] = *(const f16x8*)(sB + (wn * 128 + ni * 16 + lrow) * 64 + kc * 32 + lq * 8);
      #pragma unroll
      for (int mi = 0; mi < 4; ++mi)
        #pragma unroll
        for (int ni = 0; ni < 8; ++ni)
          acc[mi][ni] = __builtin_amdgcn_mfma_f32_16x16x32_f16(af[mi], bf[ni], acc[mi][ni], 0, 0, 0);
    }
  }

  // Y1 store (f16)
  #pragma unroll
  for (int mi = 0; mi < 4; ++mi)
    #pragma unroll
    for (int r = 0; r < 4; ++r) {
      size_t row = row0 + wm * 64 + mi * 16 + lq * 4 + r;
      #pragma unroll
      for (int ni = 0; ni < 8; ++ni)
        Y1[row * 256 + wn * 128 + ni * 16 + lrow] = (f16)acc[mi][ni][r];
    }

  // column stats: lane-local sums over 16 rows, reduce across lq via shfl_xor
  #pragma unroll
  for (int ni = 0; ni < 8; ++ni) {
    float s1 = 0.f, s2 = 0.f;
    #pragma unroll
    for (int mi = 0; mi < 4; ++mi)
      #pragma unroll
      for (int r = 0; r < 4; ++r) {
        float v = acc[mi][ni][r];
        s1 += v; s2 += v * v;
      }
    s1 += __shfl_xor(s1, 16, 64);
    s1 += __shfl_xor(s1, 32, 64);
    s2 += __shfl_xor(s2, 16, 64);
    s2 += __shfl_xor(s2, 32, 64);
    if (lane < 16) {
      int col = wn * 128 + ni * 16 + lane;
      atomicAdd(&stats[col], s1);
      atomicAdd(&stats[256 + col], s2);
    }
  }
}

// ---------------- GEMM2 fused: A = ReLU(BN1(Y1)) applied at staging time;
// Y2[M,128] f32 out + stats2 epilogue. 128x128 tile, padded LDS. ----------
__global__ __launch_bounds__(256) void gemm2_fused(const f16* __restrict__ Y1,
                                                   const f16* __restrict__ Bt,
                                                   float* __restrict__ Y2,
                                                   const float* __restrict__ stats,
                                                   const float* __restrict__ g1,
                                                   const float* __restrict__ be1,
                                                   float* __restrict__ stats2) {
  __shared__ __align__(16) f16 sA[128 * 72];
  __shared__ __align__(16) f16 sB[128 * 72];
  __shared__ float s_sc[D2_], s_sh[D2_];
  const int tid = threadIdx.x;
  const int lane = tid & 63;
  const int wave = tid >> 6;
  const int wm = wave & 1, wn = wave >> 1;
  const int lrow = lane & 15, lq = lane >> 4;
  const size_t row0 = (size_t)blockIdx.x * 128;
  const int srow = tid >> 3, scol = tid & 7;

  {
    const float invM = 1.0f / (float)M_;
    float m = stats[tid] * invM;
    float v = stats[D2_ + tid] * invM - m * m;
    float s = rsqrtf(fmaxf(v, 0.f) + 1e-5f) * g1[tid];
    s_sc[tid] = s; s_sh[tid] = be1[tid] - m * s;
  }
  __syncthreads();

  f32x4 acc[4][4] = {};

  for (int k0 = 0; k0 < 256; k0 += 64) {
    float4 sca = *(const float4*)&s_sc[k0 + scol * 8];
    float4 scb = *(const float4*)&s_sc[k0 + scol * 8 + 4];
    float4 sha = *(const float4*)&s_sh[k0 + scol * 8];
    float4 shb = *(const float4*)&s_sh[k0 + scol * 8 + 4];
    __syncthreads();
    #pragma unroll
    for (int i = 0; i < 4; ++i) {
      int r = srow + i * 32;
      f16x8 va = *(const f16x8*)(Y1 + (row0 + r) * 256 + k0 + scol * 8);
      f16x8 ta;
      ta[0] = (f16)fmaxf((float)va[0] * sca.x + sha.x, 0.f);
      ta[1] = (f16)fmaxf((float)va[1] * sca.y + sha.y, 0.f);
      ta[2] = (f16)fmaxf((float)va[2] * sca.z + sha.z, 0.f);
      ta[3] = (f16)fmaxf((float)va[3] * sca.w + sha.w, 0.f);
      ta[4] = (f16)fmaxf((float)va[4] * scb.x + shb.x, 0.f);
      ta[5] = (f16)fmaxf((float)va[5] * scb.y + shb.y, 0.f);
      ta[6] = (f16)fmaxf((float)va[6] * scb.z + shb.z, 0.f);
      ta[7] = (f16)fmaxf((float)va[7] * scb.w + shb.w, 0.f);
      *(f16x8*)(sA + r * 72 + scol * 8) = ta;
      uint4 vb = *(const uint4*)(Bt + (size_t)r * 256 + k0 + scol * 8);
      *(uint4*)(sB + r * 72 + scol * 8) = vb;
    }
    __syncthreads();
    #pragma unroll
    for (int kc = 0; kc < 2; ++kc) {
      f16x8 af[4], bf[4];
      #pragma unroll
      for (int mi = 0; mi < 4; ++mi)
        af[mi] = *(const f16x8*)(sA + (wm * 64 + mi * 16 + lrow) * 72 + kc * 32 + lq * 8);
      #pragma unroll
      for (int ni = 0; ni < 4; ++ni)
        bf[ni] = *(const f16x8*)(sB + (wn * 64 + ni * 16 + lrow) * 72 + kc * 32 + lq * 8);
      #pragma unroll
      for (int mi = 0; mi < 4; ++mi)
        #pragma unroll
        for (int ni = 0; ni < 4; ++ni)
          acc[mi][ni] = __builtin_amdgcn_mfma_f32_16x16x32_f16(af[mi], bf[ni], acc[mi][ni], 0, 0, 0);
    }
  }

  #pragma unroll
  for (int mi = 0; mi < 4; ++mi)
    #pragma unroll
    for (int ni = 0; ni < 4; ++ni)
      #pragma unroll
      for (int r = 0; r < 4; ++r) {
        size_t row = row0 + wm * 64 + mi * 16 + lq * 4 + r;
        int col = wn * 64 + ni * 16 + lrow;
        Y2[row * 128 + col] = acc[mi][ni][r];
      }

  #pragma unroll
  for (int ni = 0; ni < 4; ++ni) {
    float s1 = 0.f, s2 = 0.f;
    #pragma unroll
    for (int mi = 0; mi < 4; ++mi)
      #pragma unroll
      for (int r = 0; r < 4; ++r) {
        float v = acc[mi][ni][r];
        s1 += v; s2 += v * v;
      }
    s1 += __shfl_xor(s1, 16, 64);
    s1 += __shfl_xor(s1, 32, 64);
    s2 += __shfl_xor(s2, 16, 64);
    s2 += __shfl_xor(s2, 32, 64);
    if (lane < 16) {
      int col = wn * 64 + ni * 16 + lane;
      atomicAdd(&stats2[col], s1);
      atomicAdd(&stats2[D1_ + col], s2);
    }
  }
}

// ---------------- BN2 + ReLU + transpose to out [B,128,N] f32 ----------------
__global__ __launch_bounds__(256) void bn2_transpose(const float* __restrict__ Y2,
                                                     float* __restrict__ out,
                                                     const float* __restrict__ stats2,
                                                     const float* __restrict__ g2,
                                                     const float* __restrict__ be2) {
  __shared__ float sc[D1_], sh[D1_];
  __shared__ float tile[64][D1_ + 1];
  int t = threadIdx.x;
  const float invM = 1.0f / (float)M_;
  if (t < D1_) {
    float m = stats2[t] * invM;
    float v = stats2[D1_ + t] * invM - m * m;
    float s = rsqrtf(fmaxf(v, 0.f) + 1e-5f) * g2[t];
    sc[t] = s; sh[t] = be2[t] - m * s;
  }
  __syncthreads();
  int b = blockIdx.x >> 7;            // grid = 1024
  int n0 = (blockIdx.x & 127) * 64;
  const float* src = Y2 + ((size_t)b * N_ + n0) * D1_;
  for (int i = t; i < 64 * D1_; i += 256) {
    int nl = i >> 7, c = i & (D1_ - 1);
    float y = src[(size_t)nl * D1_ + c];
    tile[nl][c] = fmaxf(y * sc[c] + sh[c], 0.f);
  }
  __syncthreads();
  for (int i = t; i < 64 * D1_; i += 256) {
    int c = i >> 6, nl = i & 63;
    out[((size_t)b * D1_ + c) * N_ + n0 + nl] = tile[nl][c];
  }
}

extern "C" void kernel_launch(void* const* d_in, const int* in_sizes, int n_in,
                              void* d_out, int out_size, void* d_ws, size_t ws_size,
                              hipStream_t stream) {
  const float* xyz1    = (const float*)d_in[0];
  const float* xyz2    = (const float*)d_in[1];
  const float* points1 = (const float*)d_in[2];
  const float* points2 = (const float*)d_in[3];
  const float* w1      = (const float*)d_in[4];
  const float* g1      = (const float*)d_in[6];
  const float* be1     = (const float*)d_in[7];
  const float* w2      = (const float*)d_in[8];
  const float* g2      = (const float*)d_in[10];
  const float* be2     = (const float*)d_in[11];
  float* out = (float*)d_out;

  char* ws = (char*)d_ws;
  f16*   f2t   = (f16*)(ws);                  // [B,S,256] f16:   8,388,608 B
  int*   idx3  = (int*)(ws + 8388608);        // [M,3] int:         786,432
  float* w3    = (float*)(ws + 9175040);      // [M,3] f32:         786,432
  f16*   W1h   = (f16*)(ws + 9961472);        // [256,384] f16:     196,608
  f16*   W2h   = (f16*)(ws + 10158080);       // [128,256] f16:      65,536
  float* stats = (float*)(ws + 10223616);     // 768 f32:             4,096
  f16*   X1    = (f16*)(ws + 10227712);       // [M,384] f16: 50,331,648
  f16*   Y1    = (f16*)(ws + 60559360);       // [M,256] f16: 33,554,432
  float* Y2    = (float*)X1;                  // [M,128] f32 reuses X1 (dead after gemm1)

  hipMemsetAsync(stats, 0, 768 * sizeof(float), stream);
  cvt_f32_to_f16<<<384, 256, 0, stream>>>(w1, W1h, 256 * 384);
  cvt_f32_to_f16<<<128, 256, 0, stream>>>(w2, W2h, 128 * 256);
  pts2_to_f2t<<<1024, 256, 0, stream>>>(points2, f2t);
  knn3<<<1024, 256, 0, stream>>>(xyz1, xyz2, idx3, w3);
  gather_interp<<<16384, 256, 0, stream>>>(f2t, idx3, w3, X1);
  pts1_to_x1<<<2048, 256, 0, stream>>>(points1, X1);
  gemm1_fused<<<512, 256, 0, stream>>>(X1, W1h, Y1, stats);
  gemm2_fused<<<512, 256, 0, stream>>>(Y1, W2h, Y2, stats, g1, be1, stats + 512);
  bn2_transpose<<<1024, 256, 0, stream>>>(Y2, out, stats + 512, g2, be2);
}